// Round 1
// baseline (328.629 us; speedup 1.0000x reference)
//
#include <hip/hip_runtime.h>

#define T_SEQ 512
#define EMB 32
#define HID 128
#define BB 4          // batch rows per block -> 128 blocks
#define LDSW 136      // 128 + 8 pad (bf16 elems); 272B row stride -> uniform bank spread

typedef __attribute__((ext_vector_type(8))) short short8;   // 8 bf16 in 4 VGPRs
typedef __attribute__((ext_vector_type(4))) float f32x4;

__device__ __forceinline__ short f2bf(float f) {
  union { float f; unsigned u; } v; v.f = f;
  unsigned r = (v.u + 0x7FFFu + ((v.u >> 16) & 1u)) >> 16;  // RNE
  return (short)r;
}

__device__ __forceinline__ float tanh_fast(float a) {
  // tanh(a) = 1 - 2/(exp(2a)+1); exp->v_exp_f32, rcp->v_rcp_f32. Handles +-inf.
  float e = __expf(2.0f * a);
  return 1.0f - 2.0f * __builtin_amdgcn_rcpf(e + 1.0f);
}

#define MFMA(a, b, c) __builtin_amdgcn_mfma_f32_16x16x32_bf16((a), (b), (c), 0, 0, 0)

__global__ __launch_bounds__(256) void rnn_fused_kernel(
    const float* __restrict__ x, const float* __restrict__ Wx,
    const float* __restrict__ Wh, const float* __restrict__ bh,
    float* __restrict__ out) {
  // h state (bf16), double buffered. Rows BB..15 stay zero forever (zero A rows).
  __shared__ short hbuf[2][16][LDSW];

  const int tid = threadIdx.x;
  const int wid = tid >> 6;        // wave 0..3, owns cols [32w, 32w+32)
  const int lane = tid & 63;
  const int l4 = lane >> 4;        // 0..3
  const int lm = lane & 15;        // 0..15
  const int row0 = blockIdx.x * BB;
  const int colbase = wid * 32;

  for (int i = tid; i < 2 * 16 * LDSW; i += 256) ((short*)hbuf)[i] = 0;

  // ---- one-time: weight B-fragments into registers ----
  // B-frag layout (16x16x32): lane holds col = lane&15, k = (lane>>4)*8 + j
  short8 whf[2][4];  // [n-tile][k-step]
  short8 wxf[2];
  float bv[2];
#pragma unroll
  for (int nt = 0; nt < 2; ++nt) {
    const int col = colbase + 16 * nt + lm;
    bv[nt] = bh[col];
#pragma unroll
    for (int kb = 0; kb < 4; ++kb) {
      short8 f;
#pragma unroll
      for (int j = 0; j < 8; ++j)
        f[j] = f2bf(Wh[(size_t)(32 * kb + 8 * l4 + j) * HID + col]);
      whf[nt][kb] = f;
    }
    short8 fx;
#pragma unroll
    for (int j = 0; j < 8; ++j)
      fx[j] = f2bf(Wx[(size_t)(8 * l4 + j) * HID + col]);
    wxf[nt] = fx;
  }

  // ---- x prefetch: A-frag rows clamped into [0,BB) (invalid rows harmless) ----
  const int xrow = row0 + (lm & (BB - 1));
  const float* xptr = x + (size_t)xrow * T_SEQ * EMB + 8 * l4;
  f32x4 xf0 = *(const f32x4*)(xptr);
  f32x4 xf1 = *(const f32x4*)(xptr + 4);

  float* hfin = out + (size_t)512 * T_SEQ * HID;

  __syncthreads();  // LDS zero-init complete

  for (int t = 0; t < T_SEQ; ++t) {
    const int cur = t & 1, prev = cur ^ 1;

    // convert prefetched x to bf16 A-frag (row = lane&15, k = 8*(lane>>4)+j)
    short8 xa;
#pragma unroll
    for (int j = 0; j < 4; ++j) { xa[j] = f2bf(xf0[j]); xa[4 + j] = f2bf(xf1[j]); }

    if (t + 1 < T_SEQ) {  // issue next step's x loads early (h-independent)
      xf0 = *(const f32x4*)(xptr + (size_t)(t + 1) * EMB);
      xf1 = *(const f32x4*)(xptr + (size_t)(t + 1) * EMB + 4);
    }

    // x-projection + bias before the barrier (independent of h_{t-1})
    f32x4 acc0 = {bv[0], bv[0], bv[0], bv[0]};
    f32x4 acc1 = {bv[1], bv[1], bv[1], bv[1]};
    acc0 = MFMA(xa, wxf[0], acc0);
    acc1 = MFMA(xa, wxf[1], acc1);

    __syncthreads();  // hbuf[prev] (h_{t-1}) fully written; also fences WAR on hbuf[cur]

    const short* hb = &hbuf[prev][0][0];
    short8 ah[4];
#pragma unroll
    for (int kb = 0; kb < 4; ++kb)
      ah[kb] = *(const short8*)(hb + lm * LDSW + 32 * kb + 8 * l4);
#pragma unroll
    for (int kb = 0; kb < 4; ++kb) {
      acc0 = MFMA(ah[kb], whf[0][kb], acc0);
      acc1 = MFMA(ah[kb], whf[1][kb], acc1);
    }

    // C/D layout: col = lane&15, row = 4*(lane>>4)+r  -> valid rows live in l4==0
    if (l4 == 0) {
      short* hw = &hbuf[cur][0][0];
#pragma unroll
      for (int r = 0; r < BB; ++r) {
        float t0 = tanh_fast(acc0[r]);
        float t1 = tanh_fast(acc1[r]);
        hw[r * LDSW + colbase + lm] = f2bf(t0);
        hw[r * LDSW + colbase + 16 + lm] = f2bf(t1);
        const size_t o = ((size_t)(row0 + r) * T_SEQ + t) * HID;
        out[o + colbase + lm] = t0;
        out[o + colbase + 16 + lm] = t1;
        if (t == T_SEQ - 1) {
          hfin[(size_t)(row0 + r) * HID + colbase + lm] = t0;
          hfin[(size_t)(row0 + r) * HID + colbase + 16 + lm] = t1;
        }
      }
    }
  }
}

extern "C" void kernel_launch(void* const* d_in, const int* in_sizes, int n_in,
                              void* d_out, int out_size, void* d_ws, size_t ws_size,
                              hipStream_t stream) {
  const float* x  = (const float*)d_in[0];
  const float* Wx = (const float*)d_in[1];
  const float* Wh = (const float*)d_in[2];
  const float* bh = (const float*)d_in[3];
  float* out = (float*)d_out;
  (void)in_sizes; (void)n_in; (void)out_size; (void)d_ws; (void)ws_size;
  rnn_fused_kernel<<<512 / BB, 256, 0, stream>>>(x, Wx, Wh, bh, out);
}

// Round 2
// 241.841 us; speedup vs baseline: 1.3589x; 1.3589x over previous
//
#include <hip/hip_runtime.h>

#define T_SEQ 512
#define EMB 32
#define HID 128
#define BB 2          // batch rows per block -> 256 blocks (all 256 CUs)
#define LDSW 160      // row stride in bf16 elems: 320B = 80 dwords -> read banks disjoint

typedef __attribute__((ext_vector_type(8))) short short8;   // 8 bf16 in 4 VGPRs
typedef __attribute__((ext_vector_type(4))) float f32x4;

__device__ __forceinline__ short f2bf(float f) {
  union { float f; unsigned u; } v; v.f = f;
  unsigned r = (v.u + 0x7FFFu + ((v.u >> 16) & 1u)) >> 16;  // RNE
  return (short)r;
}

__device__ __forceinline__ float tanh_fast(float a) {
  // tanh(a) = 1 - 2/(exp(2a)+1); exp->v_exp_f32, rcp->v_rcp_f32.
  float e = __expf(2.0f * a);
  return 1.0f - 2.0f * __builtin_amdgcn_rcpf(e + 1.0f);
}

#define MFMA(a, b, c) __builtin_amdgcn_mfma_f32_16x16x32_bf16((a), (b), (c), 0, 0, 0)

__global__ __launch_bounds__(256) void rnn_fused_kernel(
    const float* __restrict__ x, const float* __restrict__ Wx,
    const float* __restrict__ Wh, const float* __restrict__ bh,
    float* __restrict__ out) {
  // h state (bf16), double buffered; only 2 batch rows live here.
  // A-frag rows are duplicated via (lm&1) read addressing (same-addr broadcast).
  __shared__ short hbuf[2][BB][LDSW];

  const int tid = threadIdx.x;
  const int wid = tid >> 6;        // wave 0..3, owns cols [32w, 32w+32)
  const int lane = tid & 63;
  const int l4 = lane >> 4;        // 0..3
  const int lm = lane & 15;        // 0..15
  const int row0 = blockIdx.x * BB;
  const int colbase = wid * 32;

  for (int i = tid; i < 2 * BB * LDSW; i += 256) ((short*)hbuf)[i] = 0;

  // ---- one-time: weight B-fragments into registers ----
  // B-frag layout (16x16x32): lane holds col = lane&15, k = (lane>>4)*8 + j
  short8 whf[2][4];  // [n-tile][k-step]
  short8 wxf[2];
  float bv[2];
#pragma unroll
  for (int nt = 0; nt < 2; ++nt) {
    const int col = colbase + 16 * nt + lm;
    bv[nt] = bh[col];
#pragma unroll
    for (int kb = 0; kb < 4; ++kb) {
      short8 f;
#pragma unroll
      for (int j = 0; j < 8; ++j)
        f[j] = f2bf(Wh[(size_t)(32 * kb + 8 * l4 + j) * HID + col]);
      whf[nt][kb] = f;
    }
    short8 fx;
#pragma unroll
    for (int j = 0; j < 8; ++j)
      fx[j] = f2bf(Wx[(size_t)(8 * l4 + j) * HID + col]);
    wxf[nt] = fx;
  }

  // ---- x prefetch: A-frag row lm holds batch row (lm&1) ----
  const int xrow = row0 + (lm & 1);
  const float* xptr = x + (size_t)xrow * T_SEQ * EMB + 8 * l4;
  f32x4 xf0 = *(const f32x4*)(xptr);
  f32x4 xf1 = *(const f32x4*)(xptr + 4);

  // ---- per-lane output assignment: every lane owns ONE (row,col) ----
  const int rsel = l4 & 1;         // batch row parity
  const int csel = l4 >> 1;        // which 16-col tile
  const int ocol = colbase + 16 * csel + lm;
  float* outp = out + (size_t)(row0 + rsel) * T_SEQ * HID + ocol;
  float* hfinp = out + (size_t)512 * T_SEQ * HID + (size_t)(row0 + rsel) * HID + ocol;

  __syncthreads();  // LDS zero-init complete (full barrier OK once)

#pragma unroll 2
  for (int t = 0; t < T_SEQ; ++t) {
    const int cur = t & 1, prev = cur ^ 1;

    // h A-frags first (longest latency); row = lm&1 (broadcast duplicates)
    const short* hb = &hbuf[prev][lm & 1][0];
    short8 ah[4];
#pragma unroll
    for (int kb = 0; kb < 4; ++kb)
      ah[kb] = *(const short8*)(hb + 32 * kb + 8 * l4);

    // convert prefetched x to bf16 A-frag (row = lane&15, k = 8*(lane>>4)+j)
    short8 xa;
#pragma unroll
    for (int j = 0; j < 4; ++j) { xa[j] = f2bf(xf0[j]); xa[4 + j] = f2bf(xf1[j]); }

    if (t + 1 < T_SEQ) {  // issue next step's x loads early (h-independent)
      xf0 = *(const f32x4*)(xptr + (size_t)(t + 1) * EMB);
      xf1 = *(const f32x4*)(xptr + (size_t)(t + 1) * EMB + 4);
    }

    // split accumulate chains: (x,kb0,kb1) || (kb2,kb3)
    f32x4 acc0a = {bv[0], bv[0], bv[0], bv[0]};
    f32x4 acc1a = {bv[1], bv[1], bv[1], bv[1]};
    f32x4 acc0b = {0.f, 0.f, 0.f, 0.f};
    f32x4 acc1b = {0.f, 0.f, 0.f, 0.f};
    acc0a = MFMA(xa, wxf[0], acc0a);
    acc1a = MFMA(xa, wxf[1], acc1a);
    acc0a = MFMA(ah[0], whf[0][0], acc0a);
    acc1a = MFMA(ah[0], whf[1][0], acc1a);
    acc0a = MFMA(ah[1], whf[0][1], acc0a);
    acc1a = MFMA(ah[1], whf[1][1], acc1a);
    acc0b = MFMA(ah[2], whf[0][2], acc0b);
    acc1b = MFMA(ah[2], whf[1][2], acc1b);
    acc0b = MFMA(ah[3], whf[0][3], acc0b);
    acc1b = MFMA(ah[3], whf[1][3], acc1b);

    // each lane extracts its one value (compile-time element indices only)
    float v0 = (rsel ? acc0a[1] : acc0a[0]) + (rsel ? acc0b[1] : acc0b[0]);
    float v1 = (rsel ? acc1a[1] : acc1a[0]) + (rsel ? acc1b[1] : acc1b[0]);
    float v = csel ? v1 : v0;
    float th = tanh_fast(v);

    hbuf[cur][rsel][ocol] = f2bf(th);   // 1 ds_write_b16 per lane
    outp[(size_t)t * HID] = th;          // 1 global store per lane (64B/segment)
    if (t == T_SEQ - 1) *hfinp = th;

    // LDS visibility only — do NOT drain global stores (no vmcnt wait!)
    asm volatile("s_waitcnt lgkmcnt(0)\n\ts_barrier" ::: "memory");
  }
}

extern "C" void kernel_launch(void* const* d_in, const int* in_sizes, int n_in,
                              void* d_out, int out_size, void* d_ws, size_t ws_size,
                              hipStream_t stream) {
  const float* x  = (const float*)d_in[0];
  const float* Wx = (const float*)d_in[1];
  const float* Wh = (const float*)d_in[2];
  const float* bh = (const float*)d_in[3];
  float* out = (float*)d_out;
  (void)in_sizes; (void)n_in; (void)out_size; (void)d_ws; (void)ws_size;
  rnn_fused_kernel<<<512 / BB, 256, 0, stream>>>(x, Wx, Wh, bh, out);
}